// Round 5
// baseline (105.735 us; speedup 1.0000x reference)
//
#include <hip/hip_runtime.h>
#include <hip/hip_bf16.h>

// RBF: out[b][o] = exp(-max(||x_b||^2 - 2 x_b.c_o + ||c_o||^2, 0) * exp(-2*log_sigma_o))
// A/B PROBE ROUND: R1's convert_sumsq + rbf_gemm unchanged, then rbf_gemm2 (counted-vmcnt
// 3-buffer pipeline) overwrites out with identical values. t(gemm2) = dur_us - 88.1.

#define B_ROWS 8192
#define IN_K   512
#define OUT_N  1024
#define BK     64
#define NKT    (IN_K / BK)    // 8
#define BK2    32
#define NKT2   (IN_K / BK2)   // 16

typedef __attribute__((ext_vector_type(8))) __bf16 bf16x8;
typedef __attribute__((ext_vector_type(4))) __bf16 bf16x4;
typedef __attribute__((ext_vector_type(4))) float  floatx4;

__device__ __forceinline__ void gload_lds16(const void* g, void* l) {
    __builtin_amdgcn_global_load_lds((const __attribute__((address_space(1))) void*)g,
                                     (__attribute__((address_space(3))) void*)l,
                                     16, 0, 0);
}

// ---- pass 1: convert fp32 row -> bf16 row, emit sum of squares. 1 wave per row. ----
__global__ __launch_bounds__(256) void convert_sumsq(
    const float* __restrict__ X, const float* __restrict__ C,
    __bf16* __restrict__ Xbf, __bf16* __restrict__ Cbf,
    float* __restrict__ xsq, float* __restrict__ csq)
{
    int wid  = (blockIdx.x * 256 + threadIdx.x) >> 6;   // 0..9215
    int lane = threadIdx.x & 63;
    const float* src; __bf16* dst; float* sq;
    if (wid < B_ROWS) {
        src = X + (size_t)wid * IN_K; dst = Xbf + (size_t)wid * IN_K; sq = xsq + wid;
    } else {
        int r = wid - B_ROWS;
        src = C + (size_t)r * IN_K;  dst = Cbf + (size_t)r * IN_K;  sq = csq + r;
    }
    const float4* s4 = reinterpret_cast<const float4*>(src);
    float4 a = s4[lane];
    float4 b = s4[lane + 64];
    bf16x4 va = {(__bf16)a.x, (__bf16)a.y, (__bf16)a.z, (__bf16)a.w};
    bf16x4 vb = {(__bf16)b.x, (__bf16)b.y, (__bf16)b.z, (__bf16)b.w};
    *reinterpret_cast<bf16x4*>(dst + lane * 4)       = va;
    *reinterpret_cast<bf16x4*>(dst + 256 + lane * 4) = vb;
    float s = a.x*a.x + a.y*a.y + a.z*a.z + a.w*a.w
            + b.x*b.x + b.y*b.y + b.z*b.z + b.w*b.w;
    #pragma unroll
    for (int off = 32; off; off >>= 1) s += __shfl_xor(s, off, 64);
    if (lane == 0) *sq = s;
}

// ---- R1 GEMM (baseline arm, unchanged) ----
__global__ __launch_bounds__(256, 2) void rbf_gemm(
    const __bf16* __restrict__ Xbf, const __bf16* __restrict__ Cbf,
    const float* __restrict__ LS, const float* __restrict__ xsq,
    const float* __restrict__ csq, float* __restrict__ out)
{
    __shared__ __bf16 As[2][128 * BK];
    __shared__ __bf16 Bs[2][128 * BK];

    const int tid  = threadIdx.x;
    const int sid  = blockIdx.x;
    const int bidx = (sid & 7) * 64 + (sid >> 3);
    const int bm   = bidx >> 3;
    const int bn   = bidx & 7;
    const int brow = bm * 128;
    const int bcol = bn * 128;
    const int lane = tid & 63;
    const int w    = tid >> 6;
    const int wr   = w >> 1;
    const int wc   = w & 1;
    const int l15  = lane & 15;
    const int l4   = lane >> 4;

    const int srow = tid >> 3;
    const int col8 = (((tid & 7) ^ (srow & 7)) * 8);
    const __bf16* Asrc = Xbf + (size_t)(brow + srow) * IN_K + col8;
    const __bf16* Bsrc = Cbf + (size_t)(bcol + srow) * IN_K + col8;

    auto stage = [&](int kt, int buf) {
        #pragma unroll
        for (int i = 0; i < 4; ++i)
            gload_lds16(Asrc + (size_t)i * 32 * IN_K + kt * BK, &As[buf][tid * 8 + i * 2048]);
        #pragma unroll
        for (int i = 0; i < 4; ++i)
            gload_lds16(Bsrc + (size_t)i * 32 * IN_K + kt * BK, &Bs[buf][tid * 8 + i * 2048]);
    };

    floatx4 acc[4][4];
    #pragma unroll
    for (int m = 0; m < 4; ++m)
        #pragma unroll
        for (int n = 0; n < 4; ++n)
            acc[m][n] = (floatx4){0.f, 0.f, 0.f, 0.f};

    stage(0, 0);

    #pragma unroll 1
    for (int kt = 0; kt < NKT; ++kt) {
        const int cur = kt & 1;
        __syncthreads();
        if (kt < NKT - 1) stage(kt + 1, cur ^ 1);

        #pragma unroll
        for (int ks = 0; ks < 2; ++ks) {
            bf16x8 af[4], bfr[4];
            #pragma unroll
            for (int m = 0; m < 4; ++m) {
                int r = wr * 64 + m * 16 + l15;
                int kslot = l4 + ks * 4;
                af[m] = *reinterpret_cast<const bf16x8*>(
                    &As[cur][r * BK + ((kslot ^ (r & 7)) * 8)]);
            }
            #pragma unroll
            for (int n = 0; n < 4; ++n) {
                int r = wc * 64 + n * 16 + l15;
                int kslot = l4 + ks * 4;
                bfr[n] = *reinterpret_cast<const bf16x8*>(
                    &Bs[cur][r * BK + ((kslot ^ (r & 7)) * 8)]);
            }
            #pragma unroll
            for (int m = 0; m < 4; ++m)
                #pragma unroll
                for (int n = 0; n < 4; ++n)
                    acc[m][n] = __builtin_amdgcn_mfma_f32_16x16x32_bf16(af[m], bfr[n], acc[m][n], 0, 0, 0);
        }
    }

    float xs[4][4];
    #pragma unroll
    for (int m = 0; m < 4; ++m) {
        int row0 = brow + wr * 64 + m * 16 + l4 * 4;
        #pragma unroll
        for (int r = 0; r < 4; ++r) xs[m][r] = xsq[row0 + r];
    }

    #pragma unroll
    for (int n = 0; n < 4; ++n) {
        int col   = bcol + wc * 64 + n * 16 + l15;
        float cs  = csq[col];
        float inv = __expf(-2.f * LS[col]);
        #pragma unroll
        for (int m = 0; m < 4; ++m) {
            int row0 = brow + wr * 64 + m * 16 + l4 * 4;
            #pragma unroll
            for (int r = 0; r < 4; ++r) {
                float cross = acc[m][n][r];
                float d2 = fmaxf(xs[m][r] + cs - 2.f * cross, 0.f);
                out[(size_t)(row0 + r) * OUT_N + col] = __expf(-d2 * inv);
            }
        }
    }
}

// ---- NEW: counted-vmcnt 3-buffer pipelined GEMM (T4), BK=32, raw s_barrier ----
__global__ __launch_bounds__(256) void rbf_gemm2(
    const __bf16* __restrict__ Xbf, const __bf16* __restrict__ Cbf,
    const float* __restrict__ LS, const float* __restrict__ xsq,
    const float* __restrict__ csq, float* __restrict__ out)
{
    __shared__ __align__(16) __bf16 As[3][128 * BK2];   // 8 KB each
    __shared__ __align__(16) __bf16 Bs[3][128 * BK2];

    const int tid  = threadIdx.x;
    const int sid  = blockIdx.x;
    const int bidx = (sid & 7) * 64 + (sid >> 3);   // XCD swizzle, 512 % 8 == 0 bijective
    const int bm   = bidx >> 3;
    const int bn   = bidx & 7;
    const int brow = bm * 128;
    const int bcol = bn * 128;
    const int lane = tid & 63;
    const int w    = tid >> 6;
    const int wr   = w >> 1;
    const int wc   = w & 1;
    const int l15  = lane & 15;
    const int l4   = lane >> 4;

    // Staging: 128x32 bf16 = 8KB/operand = 256thr x 16B x 2. Thread t -> LDS elem
    // t*8 + i*2048: row = t/4 + 64i, phys slot = t&3. Read phys = l4 ^ (row&3), so
    // source fetches global k-slot (t&3)^(row&3) (stays in one 128B line, coalesced).
    const int srow = tid >> 2;                        // 0..63
    const int ksl  = ((tid & 3) ^ (srow & 3)) * 8;    // inverse-swizzled k offset
    const __bf16* Asrc = Xbf + (size_t)(brow + srow) * IN_K + ksl;
    const __bf16* Bsrc = Cbf + (size_t)(bcol + srow) * IN_K + ksl;

    auto stage = [&](int kt, int buf) {               // 4 loads (2 A + 2 B)
        #pragma unroll
        for (int i = 0; i < 2; ++i)
            gload_lds16(Asrc + (size_t)i * 64 * IN_K + kt * BK2, &As[buf][tid * 8 + i * 2048]);
        #pragma unroll
        for (int i = 0; i < 2; ++i)
            gload_lds16(Bsrc + (size_t)i * 64 * IN_K + kt * BK2, &Bs[buf][tid * 8 + i * 2048]);
    };

    floatx4 acc[4][4];
    #pragma unroll
    for (int m = 0; m < 4; ++m)
        #pragma unroll
        for (int n = 0; n < 4; ++n)
            acc[m][n] = (floatx4){0.f, 0.f, 0.f, 0.f};

    // Prologue: depth-2 prefetch; ensure stage(0) done before first barrier.
    stage(0, 0);
    stage(1, 1);
    asm volatile("s_waitcnt vmcnt(4)" ::: "memory");

    #pragma unroll 1
    for (int kt = 0; kt < NKT2; ++kt) {
        int cur = kt; cur -= (cur / 3) * 3;           // kt % 3
        // barrier(kt): every wave has vmcnt-confirmed its stage(kt) loads and
        // completed (lgkmcnt'd) its buf[kt-1] reads -> buf[kt] published,
        // buf[(kt+2)%3] free to overwrite.
        __builtin_amdgcn_s_barrier();
        __builtin_amdgcn_sched_barrier(0);

        bf16x8 af[4], bfr[4];
        #pragma unroll
        for (int m = 0; m < 4; ++m) {
            int rr = wr * 64 + m * 16 + l15;
            af[m] = *reinterpret_cast<const bf16x8*>(&As[cur][rr * 32 + ((l4 ^ (rr & 3)) * 8)]);
        }
        #pragma unroll
        for (int n = 0; n < 4; ++n) {
            int rr = wc * 64 + n * 16 + l15;
            bfr[n] = *reinterpret_cast<const bf16x8*>(&Bs[cur][rr * 32 + ((l4 ^ (rr & 3)) * 8)]);
        }
        #pragma unroll
        for (int m = 0; m < 4; ++m)
            #pragma unroll
            for (int n = 0; n < 4; ++n)
                acc[m][n] = __builtin_amdgcn_mfma_f32_16x16x32_bf16(af[m], bfr[n], acc[m][n], 0, 0, 0);

        if (kt + 2 < NKT2) {
            int nb = kt + 2; nb -= (nb / 3) * 3;
            stage(kt + 2, nb);
            __builtin_amdgcn_sched_barrier(0);
            // counted wait: only stage(kt+1) (issued a full iteration ago) must
            // finish; stage(kt+2)'s 4 loads stay in flight across the barrier.
            asm volatile("s_waitcnt vmcnt(4)" ::: "memory");
        } else {
            asm volatile("s_waitcnt vmcnt(0)" ::: "memory");
        }
        __builtin_amdgcn_sched_barrier(0);
    }

    float xs[4][4];
    #pragma unroll
    for (int m = 0; m < 4; ++m) {
        int row0 = brow + wr * 64 + m * 16 + l4 * 4;
        #pragma unroll
        for (int r = 0; r < 4; ++r) xs[m][r] = xsq[row0 + r];
    }

    #pragma unroll
    for (int n = 0; n < 4; ++n) {
        int col   = bcol + wc * 64 + n * 16 + l15;
        float cs  = csq[col];
        float inv = __expf(-2.f * LS[col]);
        #pragma unroll
        for (int m = 0; m < 4; ++m) {
            int row0 = brow + wr * 64 + m * 16 + l4 * 4;
            #pragma unroll
            for (int r = 0; r < 4; ++r) {
                float d2 = fmaxf(xs[m][r] + cs - 2.f * acc[m][n][r], 0.f);
                out[(size_t)(row0 + r) * OUT_N + col] = __expf(-d2 * inv);
            }
        }
    }
}

extern "C" void kernel_launch(void* const* d_in, const int* in_sizes, int n_in,
                              void* d_out, int out_size, void* d_ws, size_t ws_size,
                              hipStream_t stream) {
    const float* X  = (const float*)d_in[0];
    const float* C  = (const float*)d_in[1];
    const float* LS = (const float*)d_in[2];
    float* out = (float*)d_out;

    float*  xsq = (float*)d_ws;
    float*  csq = (float*)((char*)d_ws + 32768);
    __bf16* Xbf = (__bf16*)((char*)d_ws + 65536);
    __bf16* Cbf = (__bf16*)((char*)d_ws + 65536 + (size_t)B_ROWS * IN_K * 2);

    convert_sumsq<<<(B_ROWS + OUT_N) / 4, 256, 0, stream>>>(X, C, Xbf, Cbf, xsq, csq);
    rbf_gemm <<<(B_ROWS / 128) * (OUT_N / 128), 256, 0, stream>>>(Xbf, Cbf, LS, xsq, csq, out);
    rbf_gemm2<<<(B_ROWS / 128) * (OUT_N / 128), 256, 0, stream>>>(Xbf, Cbf, LS, xsq, csq, out);
}

// Round 6
// 92.644 us; speedup vs baseline: 1.1413x; 1.1413x over previous
//
#include <hip/hip_runtime.h>
#include <hip/hip_bf16.h>

// RBF: out[b][o] = exp(-max(||x_b||^2 - 2 x_b.c_o + ||c_o||^2, 0) * exp(-2*log_sigma_o))
// B=8192, IN=512, OUT=1024 fp32.
// Pass 1: fused fp32->bf16 convert + row sum-of-squares (X and C) into d_ws.
// Pass 2: bf16 MFMA GEMM + RBF epilogue. 128x128 tile, 4 waves x 64x64, BK=32,
//   4-buffer LDS, depth-3 counted-vmcnt pipeline (stage(kt+3), s_waitcnt vmcnt(8)),
//   raw s_barrier (1/iter), conflict-free XOR swizzle (phys = l4 ^ ((row>>1)&3)),
//   global_load_lds dwordx4, XCD-aware block swizzle (512 % 8 == 0, bijective).

#define B_ROWS 8192
#define IN_K   512
#define OUT_N  1024
#define BK     32
#define NKT    (IN_K / BK)   // 16

typedef __attribute__((ext_vector_type(8))) __bf16 bf16x8;
typedef __attribute__((ext_vector_type(4))) __bf16 bf16x4;
typedef __attribute__((ext_vector_type(4))) float  floatx4;

__device__ __forceinline__ void gload_lds16(const void* g, void* l) {
    __builtin_amdgcn_global_load_lds((const __attribute__((address_space(1))) void*)g,
                                     (__attribute__((address_space(3))) void*)l,
                                     16, 0, 0);
}

// ---- pass 1: convert fp32 row -> bf16 row, emit sum of squares. 1 wave per row. ----
__global__ __launch_bounds__(256) void convert_sumsq(
    const float* __restrict__ X, const float* __restrict__ C,
    __bf16* __restrict__ Xbf, __bf16* __restrict__ Cbf,
    float* __restrict__ xsq, float* __restrict__ csq)
{
    int wid  = (blockIdx.x * 256 + threadIdx.x) >> 6;   // 0..9215
    int lane = threadIdx.x & 63;
    const float* src; __bf16* dst; float* sq;
    if (wid < B_ROWS) {
        src = X + (size_t)wid * IN_K; dst = Xbf + (size_t)wid * IN_K; sq = xsq + wid;
    } else {
        int r = wid - B_ROWS;
        src = C + (size_t)r * IN_K;  dst = Cbf + (size_t)r * IN_K;  sq = csq + r;
    }
    const float4* s4 = reinterpret_cast<const float4*>(src);
    float4 a = s4[lane];
    float4 b = s4[lane + 64];
    bf16x4 va = {(__bf16)a.x, (__bf16)a.y, (__bf16)a.z, (__bf16)a.w};
    bf16x4 vb = {(__bf16)b.x, (__bf16)b.y, (__bf16)b.z, (__bf16)b.w};
    *reinterpret_cast<bf16x4*>(dst + lane * 4)       = va;
    *reinterpret_cast<bf16x4*>(dst + 256 + lane * 4) = vb;
    float s = a.x*a.x + a.y*a.y + a.z*a.z + a.w*a.w
            + b.x*b.x + b.y*b.y + b.z*b.z + b.w*b.w;
    #pragma unroll
    for (int off = 32; off; off >>= 1) s += __shfl_xor(s, off, 64);
    if (lane == 0) *sq = s;
}

// ---- pass 2: depth-3 counted-vmcnt pipelined GEMM + RBF epilogue ----
__global__ __launch_bounds__(256) void rbf_gemm3(
    const __bf16* __restrict__ Xbf, const __bf16* __restrict__ Cbf,
    const float* __restrict__ LS, const float* __restrict__ xsq,
    const float* __restrict__ csq, float* __restrict__ out)
{
    __shared__ __align__(16) __bf16 As[4][128 * BK];   // 8 KB each buf
    __shared__ __align__(16) __bf16 Bs[4][128 * BK];   // total 64 KB

    const int tid  = threadIdx.x;
    const int sid  = blockIdx.x;
    const int bidx = (sid & 7) * 64 + (sid >> 3);   // XCD swizzle (bijective: 512 % 8 == 0)
    const int bm   = bidx >> 3;                      // 0..63
    const int bn   = bidx & 7;                       // 0..7
    const int brow = bm * 128;
    const int bcol = bn * 128;
    const int lane = tid & 63;
    const int w    = tid >> 6;
    const int wr   = w >> 1;                         // 2x2 waves, 64x64 each
    const int wc   = w & 1;
    const int l15  = lane & 15;
    const int l4   = lane >> 4;

    // Staging: 128x32 bf16 = 8KB/operand/tile = 256 thr x 16B x 2 loads.
    // Thread t writes LDS elems [t*8, t*8+8) + i*2048: row = t/4 + 64i, phys slot = t&3
    // (writes perfectly sequential -> conflict-free).
    // Read wants phys = l4 ^ f(row), f(row) = (row>>1)&3  (8 bank-quads, 2-way = free),
    // so the source fetches global k-slot (t&3) ^ f(srow); f invariant across i
    // (rows step by 64). Permutation stays inside one 64B span -> still coalesced.
    const int srow = tid >> 2;                                  // 0..63
    const int ksl  = (((tid & 3) ^ ((srow >> 1) & 3)) * 8);     // inverse-swizzled k offset
    const __bf16* Asrc = Xbf + (size_t)(brow + srow) * IN_K + ksl;
    const __bf16* Bsrc = Cbf + (size_t)(bcol + srow) * IN_K + ksl;

    auto stage = [&](int kt, int buf) {              // 4 loads: 2 A + 2 B
        #pragma unroll
        for (int i = 0; i < 2; ++i)
            gload_lds16(Asrc + (size_t)i * 64 * IN_K + kt * BK, &As[buf][tid * 8 + i * 2048]);
        #pragma unroll
        for (int i = 0; i < 2; ++i)
            gload_lds16(Bsrc + (size_t)i * 64 * IN_K + kt * BK, &Bs[buf][tid * 8 + i * 2048]);
    };

    floatx4 acc[4][4];
    #pragma unroll
    for (int m = 0; m < 4; ++m)
        #pragma unroll
        for (int n = 0; n < 4; ++n)
            acc[m][n] = (floatx4){0.f, 0.f, 0.f, 0.f};

    // Prologue: depth-3 prefetch; only stage(0) must be resident before iter 0.
    stage(0, 0);
    stage(1, 1);
    stage(2, 2);
    asm volatile("s_waitcnt vmcnt(8)" ::: "memory");   // stage(0) done; 1,2 in flight

    #pragma unroll 1
    for (int kt = 0; kt < NKT; ++kt) {
        const int cur = kt & 3;
        // barrier(kt): all waves vmcnt-confirmed their stage(kt) loads (at iter kt-1)
        // and finished reading buf[kt-1] (lgkmcnt before MFMA) -> buf[kt] published,
        // buf[(kt+3)&3] (= buf[(kt-1)&3]) free to overwrite.
        __builtin_amdgcn_s_barrier();
        __builtin_amdgcn_sched_barrier(0);

        bf16x8 af[4], bfr[4];
        #pragma unroll
        for (int m = 0; m < 4; ++m) {
            int rr = wr * 64 + m * 16 + l15;
            af[m] = *reinterpret_cast<const bf16x8*>(
                &As[cur][rr * BK + ((l4 ^ ((rr >> 1) & 3)) * 8)]);
        }
        #pragma unroll
        for (int n = 0; n < 4; ++n) {
            int rr = wc * 64 + n * 16 + l15;
            bfr[n] = *reinterpret_cast<const bf16x8*>(
                &Bs[cur][rr * BK + ((l4 ^ ((rr >> 1) & 3)) * 8)]);
        }
        #pragma unroll
        for (int m = 0; m < 4; ++m)
            #pragma unroll
            for (int n = 0; n < 4; ++n)
                acc[m][n] = __builtin_amdgcn_mfma_f32_16x16x32_bf16(af[m], bfr[n], acc[m][n], 0, 0, 0);

        if (kt + 3 < NKT) {
            stage(kt + 3, (kt + 3) & 3);
            __builtin_amdgcn_sched_barrier(0);
            // counted wait: ensures stage(kt+1) (issued 2 iters ago) is resident;
            // stage(kt+2) and stage(kt+3) (8 loads) stay in flight across the barrier.
            asm volatile("s_waitcnt vmcnt(8)" ::: "memory");
        } else if (kt + 2 < NKT) {
            asm volatile("s_waitcnt vmcnt(4)" ::: "memory");   // stage(kt+1) done
        } else if (kt + 1 < NKT) {
            asm volatile("s_waitcnt vmcnt(0)" ::: "memory");   // last stage done
        }
        __builtin_amdgcn_sched_barrier(0);
    }

    // Epilogue: d2 = max(xsq + csq - 2*cross, 0); out = exp(-d2 * exp(-2*ls))
    float xs[4][4];
    #pragma unroll
    for (int m = 0; m < 4; ++m) {
        int row0 = brow + wr * 64 + m * 16 + l4 * 4;
        #pragma unroll
        for (int r = 0; r < 4; ++r) xs[m][r] = xsq[row0 + r];
    }

    #pragma unroll
    for (int n = 0; n < 4; ++n) {
        int col   = bcol + wc * 64 + n * 16 + l15;
        float cs  = csq[col];
        float inv = __expf(-2.f * LS[col]);
        #pragma unroll
        for (int m = 0; m < 4; ++m) {
            int row0 = brow + wr * 64 + m * 16 + l4 * 4;
            #pragma unroll
            for (int r = 0; r < 4; ++r) {
                float d2 = fmaxf(xs[m][r] + cs - 2.f * acc[m][n][r], 0.f);
                out[(size_t)(row0 + r) * OUT_N + col] = __expf(-d2 * inv);
            }
        }
    }
}

extern "C" void kernel_launch(void* const* d_in, const int* in_sizes, int n_in,
                              void* d_out, int out_size, void* d_ws, size_t ws_size,
                              hipStream_t stream) {
    const float* X  = (const float*)d_in[0];   // input   [8192][512]
    const float* C  = (const float*)d_in[1];   // centres [1024][512]
    const float* LS = (const float*)d_in[2];   // log_sigmas [1024]
    float* out = (float*)d_out;

    float*  xsq = (float*)d_ws;                                   // 8192 f32
    float*  csq = (float*)((char*)d_ws + 32768);                  // 1024 f32
    __bf16* Xbf = (__bf16*)((char*)d_ws + 65536);                 // 8.4 MB
    __bf16* Cbf = (__bf16*)((char*)d_ws + 65536 + (size_t)B_ROWS * IN_K * 2); // 1 MB

    convert_sumsq<<<(B_ROWS + OUT_N) / 4, 256, 0, stream>>>(X, C, Xbf, Cbf, xsq, csq);
    rbf_gemm3<<<(B_ROWS / 128) * (OUT_N / 128), 256, 0, stream>>>(Xbf, Cbf, LS, xsq, csq, out);
}